// Round 7
// baseline (14678.151 us; speedup 1.0000x reference)
//
#include <hip/hip_runtime.h>

#define T_SZ 65536
#define K_SZ 2048
#define D_SZ 256

typedef unsigned short u16;
typedef _Float16 f16;
typedef f16 f16x8 __attribute__((ext_vector_type(8)));
typedef float f32x4 __attribute__((ext_vector_type(4)));

// Candidate ring capacity (per 64-row block). Stale-gate load measured in the
// R3-structure at ~250-500 per 64 rows; 1024 is 2-4x headroom. Overflow ->
// exact full scan fallback (correct, slow, statistically unreachable).
#define RINGCAP 1024

#define GLOAD_LDS16(g, l)                                                  \
  __builtin_amdgcn_global_load_lds(                                        \
      (const __attribute__((address_space(1))) unsigned int*)(g),          \
      (__attribute__((address_space(3))) unsigned int*)(l), 16, 0, 0)

// bank-swizzle key for 16B k-groups within a 64B row. Baked into the global
// fp16 images by the conv kernels and inverted at fragment-read time (G21:
// both-sides-or-neither), so it is correctness-neutral by construction.
__device__ __forceinline__ int swz4(int r) { return (r & 3) ^ ((r >> 2) & 3); }

// numpy pairwise_sum replica for 128 contiguous squared elements, float4
// loads (identical FP op sequence to the harness-verified scalar version).
__device__ __forceinline__ float pairwise128_sq_v4(const float4* __restrict__ a4) {
#pragma clang fp contract(off)
  float4 va = a4[0], vb = a4[1];
  float r0 = va.x * va.x, r1 = va.y * va.y, r2 = va.z * va.z, r3 = va.w * va.w;
  float r4 = vb.x * vb.x, r5 = vb.y * vb.y, r6 = vb.z * vb.z, r7 = vb.w * vb.w;
#pragma unroll
  for (int i = 2; i < 32; i += 2) {
    float4 c = a4[i], d = a4[i + 1];
    r0 += c.x * c.x;
    r1 += c.y * c.y;
    r2 += c.z * c.z;
    r3 += c.w * c.w;
    r4 += d.x * d.x;
    r5 += d.y * d.y;
    r6 += d.z * d.z;
    r7 += d.w * d.w;
  }
  return ((r0 + r1) + (r2 + r3)) + ((r4 + r5) + (r6 + r7));
}

// Same exact chain + loose |x| sum (only feeds our own rigorous error bound).
__device__ __forceinline__ float2 pairwise128_sq_abs_v4(const float4* __restrict__ a4) {
#pragma clang fp contract(off)
  float4 va = a4[0], vb = a4[1];
  float r0 = va.x * va.x, r1 = va.y * va.y, r2 = va.z * va.z, r3 = va.w * va.w;
  float r4 = vb.x * vb.x, r5 = vb.y * vb.y, r6 = vb.z * vb.z, r7 = vb.w * vb.w;
  float s0 = fabsf(va.x) + fabsf(va.y), s1 = fabsf(va.z) + fabsf(va.w);
  float s2 = fabsf(vb.x) + fabsf(vb.y), s3 = fabsf(vb.z) + fabsf(vb.w);
#pragma unroll
  for (int i = 2; i < 32; i += 2) {
    float4 c = a4[i], d = a4[i + 1];
    r0 += c.x * c.x;
    r1 += c.y * c.y;
    r2 += c.z * c.z;
    r3 += c.w * c.w;
    r4 += d.x * d.x;
    r5 += d.y * d.y;
    r6 += d.z * d.z;
    r7 += d.w * d.w;
    s0 += fabsf(c.x) + fabsf(c.y);
    s1 += fabsf(c.z) + fabsf(c.w);
    s2 += fabsf(d.x) + fabsf(d.y);
    s3 += fabsf(d.z) + fabsf(d.w);
  }
  float2 res;
  res.x = ((r0 + r1) + (r2 + r3)) + ((r4 + r5) + (r6 + r7));
  res.y = (s0 + s1) + (s2 + s3);
  return res;
}

__global__ void esq_kernel(const float* __restrict__ e, float* __restrict__ esq) {
  int k = blockIdx.x * 64 + threadIdx.x;
  const float4* er = reinterpret_cast<const float4*>(e + (size_t)k * D_SZ);
  esq[k] = pairwise128_sq_v4(er) + pairwise128_sq_v4(er + 32);
}

// E: fp32 rows -> pre-tiled, pre-swizzled fp16 image (RNE via v_cvt_f16_f32).
// Per 128-row tile (32768 u16): [kstep 0..7][row 0..127][G 0..3][j 0..7],
// element (row, k = kstep*32 + 8*(G ^ swz4(row)) + j).
__global__ __launch_bounds__(256) void conv_e_kernel(const float* __restrict__ src,
                                                     u16* __restrict__ dst) {
  const int tile = blockIdx.x, tid = threadIdx.x;
  const float4* s4 = reinterpret_cast<const float4*>(src);
  u16* dt = dst + (size_t)tile * 32768;
#pragma unroll 1
  for (int it = 0; it < 16; ++it) {
    int idx = tid + it * 256;  // 0..4095
    int G = idx & 3, row = (idx >> 2) & 127, step = idx >> 9;  // step 0..7
    int srow = tile * 128 + row;
    int kb = step * 32 + 8 * (G ^ swz4(row));
    float4 a = s4[srow * 64 + (kb >> 2)];
    float4 b = s4[srow * 64 + (kb >> 2) + 1];
    float v[8] = {a.x, a.y, a.z, a.w, b.x, b.y, b.z, b.w};
    union { f16 h[8]; uint4 vec; } pk;
#pragma unroll
    for (int j = 0; j < 8; ++j) pk.h[j] = (f16)v[j];
    *reinterpret_cast<uint4*>(dt + (size_t)step * 4096 + row * 32 + G * 8) = pk.vec;
  }
}

// X: same format, 64-row tiles (16384 u16 payload padded to 32768-u16 stride so
// tile b sits inside block b's OWN 64KB output region: no cross-block hazard).
__global__ __launch_bounds__(256) void conv_x_kernel(const float* __restrict__ src,
                                                     u16* __restrict__ dst) {
  const int tile = blockIdx.x, tid = threadIdx.x;
  const float4* s4 = reinterpret_cast<const float4*>(src);
  u16* dt = dst + (size_t)tile * 32768;
#pragma unroll 1
  for (int it = 0; it < 8; ++it) {
    int idx = tid + it * 256;  // 0..2047
    int G = idx & 3, row = (idx >> 2) & 63, step = idx >> 8;  // step 0..7
    int srow = tile * 64 + row;
    int kb = step * 32 + 8 * (G ^ swz4(row));
    float4 a = s4[srow * 64 + (kb >> 2)];
    float4 b = s4[srow * 64 + (kb >> 2) + 1];
    float v[8] = {a.x, a.y, a.z, a.w, b.x, b.y, b.z, b.w};
    union { f16 h[8]; uint4 vec; } pk;
#pragma unroll
    for (int j = 0; j < 8; ++j) pk.h[j] = (f16)v[j];
    *reinterpret_cast<uint4*>(dt + (size_t)step * 2048 + row * 32 + G * 8) = pk.vec;
  }
}

// Exact cross term: sequential fmaf chain over d=0..255 -- bit-identical to the
// harness-verified chain from previous rounds.
__device__ __forceinline__ float exact_cross(const float4* __restrict__ x4,
                                             const float4* __restrict__ e4,
                                             int grow, int code) {
  const float4* xr = x4 + (size_t)grow * 64;
  const float4* er = e4 + (size_t)code * 64;
  float acc = 0.0f;
#pragma unroll 8
  for (int t = 0; t < 64; ++t) {
    float4 a = xr[t], b = er[t];
    acc = __builtin_fmaf(a.x, b.x, acc);
    acc = __builtin_fmaf(a.y, b.y, acc);
    acc = __builtin_fmaf(a.z, b.z, acc);
    acc = __builtin_fmaf(a.w, b.w, acc);
  }
  return acc;
}

// Fused: fp16 MFMA GEMM with BOTH operands LDS-resident (A 32KB loaded once,
// B streamed 3-deep, 8KB per kstep) -- zero per-thread fragment arrays, so
// nothing can spill (the R4/R5 killer: af[] demoted to scratch). Single-pass
// stale-gated ring (R3-proven), exact rescoring, gather + STE output.
// Block = 256 thr (2x2 waves; wave tile 32 rows x 64 cols), grid 1024,
// LDS 63KB -> 2 blocks/CU.
__global__ __launch_bounds__(256, 2) void vq_mfma_kernel(
    const float* __restrict__ x, const float* __restrict__ e,
    const u16* __restrict__ Xh, const u16* __restrict__ Eh,
    const float* __restrict__ esq_g, float* __restrict__ out,
    float* __restrict__ outIdx) {
  __shared__ __align__(16) u16 As[8][64][32];   // 32KB: [ks][row][Gj]
  __shared__ __align__(16) u16 Bs[3][4096];     // 3 x 8KB: [col 0..127][Gj]
  __shared__ float xsq_s[64], th_s[64];
  __shared__ unsigned rm1_u[64];                // running min dist (uint-ordered)
  __shared__ unsigned ring[RINGCAP];
  __shared__ unsigned long long ebest[64];
  __shared__ int fidx[64];
  __shared__ unsigned ringcnt;

  const int tid = threadIdx.x;
  const int lane = tid & 63;
  const int wid = tid >> 6;
  const int wm = wid >> 1, wn = wid & 1;  // 2x2 wave grid
  const int rowbase = blockIdx.x * 64;

  if (tid == 0) ringcnt = 0;
  if (tid < 64) {
    ebest[tid] = ~0ull;
    rm1_u[tid] = 0x7F7FFFFFu;  // +FLT_MAX
  }

  // ---- A tile: linear 32KB copy image->LDS (wave-uniform base + lane*16).
  // R6 BUG WAS HERE: bound must be 8 (8 iters x 4 waves x 1KB = 32KB exactly);
  // 16 overflowed As by 32KB, clobbering Bs + all scalar LDS arrays. ----
  const u16* Atile = Xh + (size_t)blockIdx.x * 32768;
  u16* AsF = &As[0][0][0];
#pragma unroll
  for (int r = 0; r < 8; ++r)
    GLOAD_LDS16(Atile + r * 2048 + wid * 512 + lane * 8, AsF + r * 2048 + wid * 512);

  // ---- B pipeline start (kstep slice gs: 8KB at Eh + gs*4096) ----
  auto stage = [&](int bufi, int gs) {
    const u16* g = Eh + (size_t)gs * 4096 + wid * 1024 + lane * 8;
    u16* l = &Bs[bufi][wid * 1024];
    GLOAD_LDS16(g, l);
    GLOAD_LDS16(g + 512, l + 512);
  };
  stage(0, 0);
  stage(1, 1);

  const float4* x4 = reinterpret_cast<const float4*>(x);
  if (tid < 64) {
    const float4* xr = x4 + (size_t)(rowbase + tid) * 64;
    float2 p0 = pairwise128_sq_abs_v4(xr);
    float2 p1 = pairwise128_sq_abs_v4(xr + 32);
    xsq_s[tid] = p0.x + p1.x;
    // Rigorous per-row band threshold (>=2x margin over the derived
    // |approx-exact| dist bound 1.94e-6*Sa + 1.24e-4). Harness-proven in three
    // prior passing rounds -- do not tighten.
    th_s[tid] = 4.0e-6f * (p0.y + p1.y) + 4.0e-4f;
  }

  // per-thread constant LDS offsets (u16 units)
  int offA[2], offB[4];
#pragma unroll
  for (int mf = 0; mf < 2; ++mf) {
    const int row = wm * 32 + mf * 16 + (lane & 15);
    offA[mf] = row * 32 + (((lane >> 4) ^ swz4(row)) * 8);
  }
#pragma unroll
  for (int nf = 0; nf < 4; ++nf) {
    const int cl = wn * 64 + nf * 16 + (lane & 15);
    offB[nf] = cl * 32 + (((lane >> 4) ^ swz4(cl)) * 8);
  }

  f32x4 acc[2][4];
#pragma unroll
  for (int mf = 0; mf < 2; ++mf)
#pragma unroll
    for (int nf = 0; nf < 4; ++nf) acc[mf][nf] = (f32x4){0.f, 0.f, 0.f, 0.f};

  asm volatile("s_waitcnt vmcnt(0)");
  __syncthreads();

  const volatile unsigned* rmv = rm1_u;
  int bufc = 0;
#pragma unroll 1
  for (int chunk = 0; chunk < 16; ++chunk) {
    // esq loads issued at chunk start; oldest in the VMEM queue, so the
    // per-kstep vmcnt(4) drains them without draining the stage pipeline.
    float esq_c[4];
#pragma unroll
    for (int nf = 0; nf < 4; ++nf)
      esq_c[nf] = esq_g[chunk * 128 + wn * 64 + nf * 16 + (lane & 15)];
#pragma unroll
    for (int ks = 0; ks < 8; ++ks) {
      const int gs = chunk * 8 + ks;
      const bool dostage = (gs + 2 < 128);
      if (dostage) {
        int b2 = bufc + 2;
        if (b2 >= 3) b2 -= 3;
        stage(b2, gs + 2);
      }
      const u16* aa = &As[ks][0][0];
      const u16* bb = &Bs[bufc][0];
      f16x8 afr[2], bfr[4];
#pragma unroll
      for (int mf = 0; mf < 2; ++mf)
        afr[mf] = *reinterpret_cast<const f16x8*>(aa + offA[mf]);
#pragma unroll
      for (int nf = 0; nf < 4; ++nf)
        bfr[nf] = *reinterpret_cast<const f16x8*>(bb + offB[nf]);
#pragma unroll
      for (int mf = 0; mf < 2; ++mf)
#pragma unroll
        for (int nf = 0; nf < 4; ++nf)
          acc[mf][nf] = __builtin_amdgcn_mfma_f32_16x16x32_f16(
              afr[mf], bfr[nf], acc[mf][nf], 0, 0, 0);
      if (dostage) asm volatile("s_waitcnt vmcnt(4)");
      else asm volatile("s_waitcnt vmcnt(0)");
      __builtin_amdgcn_s_barrier();
      if (++bufc == 3) bufc = 0;
    }
    // ---- single-pass epilogue: stale-gated ring + running-min update.
    // Sound: gate rm >= final global min at all times, th >= 2*err ->
    // true winner and all potential ties are always recorded. ----
    const int cbase = chunk * 128 + wn * 64;
#pragma unroll
    for (int mf = 0; mf < 2; ++mf) {
#pragma unroll
      for (int rg = 0; rg < 4; ++rg) {
        const int row = wm * 32 + mf * 16 + (lane >> 4) * 4 + rg;  // C layout (m89)
        const float xq = xsq_s[row];
        const float rm = __uint_as_float(rmv[row]);  // stale-tolerant (monotone)
        const float gate = rm + th_s[row];
        float dv[4];
#pragma unroll
        for (int nf = 0; nf < 4; ++nf)
          dv[nf] = (xq - 2.0f * acc[mf][nf][rg]) + esq_c[nf];
#pragma unroll
        for (int nf = 0; nf < 4; ++nf) {
          if (dv[nf] <= gate) {
            unsigned slot = atomicAdd(&ringcnt, 1u);
            if (slot < RINGCAP)
              ring[slot] = ((unsigned)row << 11) |
                           (unsigned)(cbase + nf * 16 + (lane & 15));
          }
        }
        const float dmin = fminf(fminf(dv[0], dv[1]), fminf(dv[2], dv[3]));
        if (dmin < rm) atomicMin(&rm1_u[row], __float_as_uint(dmin));
#pragma unroll
        for (int nf = 0; nf < 4; ++nf) acc[mf][nf][rg] = 0.0f;
      }
    }
  }
  __syncthreads();

  // ---- exact rescoring of every ring entry (winner + all ties provably in) --
  const float4* e4 = reinterpret_cast<const float4*>(e);
  const unsigned cnt = ringcnt;
  if (cnt <= RINGCAP) {
    for (unsigned i = tid; i < cnt; i += 256) {
      const unsigned ent = ring[i];
      const int row = (int)(ent >> 11), code = (int)(ent & 2047u);
      const float cr = exact_cross(x4, e4, rowbase + row, code);
      const float d = (xsq_s[row] - 2.0f * cr) + esq_g[code];
      const unsigned long long key =
          (((unsigned long long)__float_as_uint(d)) << 32) | (unsigned)code;
      atomicMin(&ebest[row], key);  // min dist, tie -> lowest code (np rule)
    }
  } else {  // overflow (statistically unreachable): full exact scan
#pragma unroll 1
    for (int row = 0; row < 64; ++row) {
      for (int code = tid; code < K_SZ; code += 256) {
        const float cr = exact_cross(x4, e4, rowbase + row, code);
        const float d = (xsq_s[row] - 2.0f * cr) + esq_g[code];
        const unsigned long long key =
            (((unsigned long long)__float_as_uint(d)) << 32) | (unsigned)code;
        atomicMin(&ebest[row], key);
      }
    }
  }
  __syncthreads();
  if (tid < 64) fidx[tid] = (int)(ebest[tid] & 2047ull);
  __syncthreads();

  // ---- output: gather + STE, fully coalesced; overwrites this block's own
  // (already fully consumed) Xh tile region ----
  float4* out4 = reinterpret_cast<float4*>(out);
#pragma unroll 1
  for (int i = tid; i < 64 * 64; i += 256) {
    const int row = i >> 6, q = i & 63;
    const int idx = fidx[row];
    float4 xv = x4[(size_t)(rowbase + row) * 64 + q];
    float4 qv = e4[(size_t)idx * 64 + q];
    float4 o;
    o.x = xv.x + (qv.x - xv.x);
    o.y = xv.y + (qv.y - xv.y);
    o.z = xv.z + (qv.z - xv.z);
    o.w = xv.w + (qv.w - xv.w);
    out4[(size_t)(rowbase + row) * 64 + q] = o;
    if (q == 0) outIdx[rowbase + row] = (float)idx;
  }
}

extern "C" void kernel_launch(void* const* d_in, const int* in_sizes, int n_in,
                              void* d_out, int out_size, void* d_ws, size_t ws_size,
                              hipStream_t stream) {
  const float* x = (const float*)d_in[0];  // (65536, 256) fp32
  const float* e = (const float*)d_in[1];  // (2048, 256) fp32
  float* out = (float*)d_out;              // [T*D quantized | T indices-as-float]
  float* outIdx = out + (size_t)T_SZ * D_SZ;

  float* esq = (float*)d_ws;     // 2048 floats
  u16* Eh = (u16*)(esq + K_SZ);  // 1 MB fp16 codebook image
  // Xh (fp16 x image, 64KB-stride tiles) lives in the quantized-output region:
  // block b reads only tile b (prologue) and overwrites that region at the end.
  u16* Xh = (u16*)out;

  conv_x_kernel<<<T_SZ / 64, 256, 0, stream>>>(x, Xh);
  conv_e_kernel<<<K_SZ / 128, 256, 0, stream>>>(e, Eh);
  esq_kernel<<<K_SZ / 64, 64, 0, stream>>>(e, esq);
  vq_mfma_kernel<<<T_SZ / 64, 256, 0, stream>>>(x, e, Xh, Eh, esq, out, outIdx);
}

// Round 8
// 439.206 us; speedup vs baseline: 33.4197x; 33.4197x over previous
//
#include <hip/hip_runtime.h>

#define T_SZ 65536
#define K_SZ 2048
#define D_SZ 256

typedef unsigned short u16;
typedef _Float16 f16;
typedef f16 f16x8 __attribute__((ext_vector_type(8)));
typedef float f32x4 __attribute__((ext_vector_type(4)));

// Candidate ring capacity (per 64-row block). With the post-chunk-min gate
// (two-pass epilogue, R5-proven) the load is ~winners + near-ties; 1024 is
// >4x headroom. Overflow -> exact full scan fallback (correct, slow,
// statistically unreachable WITH the warmed gate; R7 proved the fallback
// works -- and that an unwarmed gate floods the ring at chunk 0).
#define RINGCAP 1024

#define GLOAD_LDS16(g, l)                                                  \
  __builtin_amdgcn_global_load_lds(                                        \
      (const __attribute__((address_space(1))) unsigned int*)(g),          \
      (__attribute__((address_space(3))) unsigned int*)(l), 16, 0, 0)

// bank-swizzle key for 16B k-groups within a 64B row. Baked into the global
// fp16 images by the conv kernels and inverted at fragment-read time (G21:
// both-sides-or-neither), so it is correctness-neutral by construction.
__device__ __forceinline__ int swz4(int r) { return (r & 3) ^ ((r >> 2) & 3); }

// numpy pairwise_sum replica for 128 contiguous squared elements, float4
// loads (identical FP op sequence to the harness-verified scalar version).
__device__ __forceinline__ float pairwise128_sq_v4(const float4* __restrict__ a4) {
#pragma clang fp contract(off)
  float4 va = a4[0], vb = a4[1];
  float r0 = va.x * va.x, r1 = va.y * va.y, r2 = va.z * va.z, r3 = va.w * va.w;
  float r4 = vb.x * vb.x, r5 = vb.y * vb.y, r6 = vb.z * vb.z, r7 = vb.w * vb.w;
#pragma unroll
  for (int i = 2; i < 32; i += 2) {
    float4 c = a4[i], d = a4[i + 1];
    r0 += c.x * c.x;
    r1 += c.y * c.y;
    r2 += c.z * c.z;
    r3 += c.w * c.w;
    r4 += d.x * d.x;
    r5 += d.y * d.y;
    r6 += d.z * d.z;
    r7 += d.w * d.w;
  }
  return ((r0 + r1) + (r2 + r3)) + ((r4 + r5) + (r6 + r7));
}

// Same exact chain + loose |x| sum (only feeds our own rigorous error bound).
__device__ __forceinline__ float2 pairwise128_sq_abs_v4(const float4* __restrict__ a4) {
#pragma clang fp contract(off)
  float4 va = a4[0], vb = a4[1];
  float r0 = va.x * va.x, r1 = va.y * va.y, r2 = va.z * va.z, r3 = va.w * va.w;
  float r4 = vb.x * vb.x, r5 = vb.y * vb.y, r6 = vb.z * vb.z, r7 = vb.w * vb.w;
  float s0 = fabsf(va.x) + fabsf(va.y), s1 = fabsf(va.z) + fabsf(va.w);
  float s2 = fabsf(vb.x) + fabsf(vb.y), s3 = fabsf(vb.z) + fabsf(vb.w);
#pragma unroll
  for (int i = 2; i < 32; i += 2) {
    float4 c = a4[i], d = a4[i + 1];
    r0 += c.x * c.x;
    r1 += c.y * c.y;
    r2 += c.z * c.z;
    r3 += c.w * c.w;
    r4 += d.x * d.x;
    r5 += d.y * d.y;
    r6 += d.z * d.z;
    r7 += d.w * d.w;
    s0 += fabsf(c.x) + fabsf(c.y);
    s1 += fabsf(c.z) + fabsf(c.w);
    s2 += fabsf(d.x) + fabsf(d.y);
    s3 += fabsf(d.z) + fabsf(d.w);
  }
  float2 res;
  res.x = ((r0 + r1) + (r2 + r3)) + ((r4 + r5) + (r6 + r7));
  res.y = (s0 + s1) + (s2 + s3);
  return res;
}

__global__ void esq_kernel(const float* __restrict__ e, float* __restrict__ esq) {
  int k = blockIdx.x * 64 + threadIdx.x;
  const float4* er = reinterpret_cast<const float4*>(e + (size_t)k * D_SZ);
  esq[k] = pairwise128_sq_v4(er) + pairwise128_sq_v4(er + 32);
}

// E: fp32 rows -> pre-tiled, pre-swizzled fp16 image (RNE via v_cvt_f16_f32).
// Per 128-row tile (32768 u16): [kstep 0..7][row 0..127][G 0..3][j 0..7],
// element (row, k = kstep*32 + 8*(G ^ swz4(row)) + j).
__global__ __launch_bounds__(256) void conv_e_kernel(const float* __restrict__ src,
                                                     u16* __restrict__ dst) {
  const int tile = blockIdx.x, tid = threadIdx.x;
  const float4* s4 = reinterpret_cast<const float4*>(src);
  u16* dt = dst + (size_t)tile * 32768;
#pragma unroll 1
  for (int it = 0; it < 16; ++it) {
    int idx = tid + it * 256;  // 0..4095
    int G = idx & 3, row = (idx >> 2) & 127, step = idx >> 9;  // step 0..7
    int srow = tile * 128 + row;
    int kb = step * 32 + 8 * (G ^ swz4(row));
    float4 a = s4[srow * 64 + (kb >> 2)];
    float4 b = s4[srow * 64 + (kb >> 2) + 1];
    float v[8] = {a.x, a.y, a.z, a.w, b.x, b.y, b.z, b.w};
    union { f16 h[8]; uint4 vec; } pk;
#pragma unroll
    for (int j = 0; j < 8; ++j) pk.h[j] = (f16)v[j];
    *reinterpret_cast<uint4*>(dt + (size_t)step * 4096 + row * 32 + G * 8) = pk.vec;
  }
}

// X: same format, 64-row tiles (16384 u16 payload padded to 32768-u16 stride so
// tile b sits inside block b's OWN 64KB output region: no cross-block hazard).
__global__ __launch_bounds__(256) void conv_x_kernel(const float* __restrict__ src,
                                                     u16* __restrict__ dst) {
  const int tile = blockIdx.x, tid = threadIdx.x;
  const float4* s4 = reinterpret_cast<const float4*>(src);
  u16* dt = dst + (size_t)tile * 32768;
#pragma unroll 1
  for (int it = 0; it < 8; ++it) {
    int idx = tid + it * 256;  // 0..2047
    int G = idx & 3, row = (idx >> 2) & 63, step = idx >> 8;  // step 0..7
    int srow = tile * 64 + row;
    int kb = step * 32 + 8 * (G ^ swz4(row));
    float4 a = s4[srow * 64 + (kb >> 2)];
    float4 b = s4[srow * 64 + (kb >> 2) + 1];
    float v[8] = {a.x, a.y, a.z, a.w, b.x, b.y, b.z, b.w};
    union { f16 h[8]; uint4 vec; } pk;
#pragma unroll
    for (int j = 0; j < 8; ++j) pk.h[j] = (f16)v[j];
    *reinterpret_cast<uint4*>(dt + (size_t)step * 2048 + row * 32 + G * 8) = pk.vec;
  }
}

// Exact cross term: sequential fmaf chain over d=0..255 -- bit-identical to the
// harness-verified chain from previous rounds.
__device__ __forceinline__ float exact_cross(const float4* __restrict__ x4,
                                             const float4* __restrict__ e4,
                                             int grow, int code) {
  const float4* xr = x4 + (size_t)grow * 64;
  const float4* er = e4 + (size_t)code * 64;
  float acc = 0.0f;
#pragma unroll 8
  for (int t = 0; t < 64; ++t) {
    float4 a = xr[t], b = er[t];
    acc = __builtin_fmaf(a.x, b.x, acc);
    acc = __builtin_fmaf(a.y, b.y, acc);
    acc = __builtin_fmaf(a.z, b.z, acc);
    acc = __builtin_fmaf(a.w, b.w, acc);
  }
  return acc;
}

// Fused: fp16 MFMA GEMM with BOTH operands LDS-resident (A 32KB loaded once,
// B streamed 3-deep, 8KB per kstep) -- zero per-thread fragment arrays, so
// nothing can spill (R7 confirmed: WRITE_SIZE dropped to ideal). Two-pass
// post-chunk-min gated ring (R5-proven: warms the gate BEFORE recording, so
// chunk 0 cannot flood the ring -- the R7 14.7ms failure mode), exact
// rescoring, gather + STE output.
// Block = 256 thr (2x2 waves; wave tile 32 rows x 64 cols), grid 1024,
// LDS 63KB -> 2 blocks/CU.
__global__ __launch_bounds__(256, 2) void vq_mfma_kernel(
    const float* __restrict__ x, const float* __restrict__ e,
    const u16* __restrict__ Xh, const u16* __restrict__ Eh,
    const float* __restrict__ esq_g, float* __restrict__ out,
    float* __restrict__ outIdx) {
  __shared__ __align__(16) u16 As[8][64][32];   // 32KB: [ks][row][Gj]
  __shared__ __align__(16) u16 Bs[3][4096];     // 3 x 8KB: [col 0..127][Gj]
  __shared__ float xsq_s[64], th_s[64];
  __shared__ unsigned rm1_u[64];                // running min dist (uint-ordered)
  __shared__ unsigned ring[RINGCAP];
  __shared__ unsigned long long ebest[64];
  __shared__ int fidx[64];
  __shared__ unsigned ringcnt;

  const int tid = threadIdx.x;
  const int lane = tid & 63;
  const int wid = tid >> 6;
  const int wm = wid >> 1, wn = wid & 1;  // 2x2 wave grid
  const int rowbase = blockIdx.x * 64;

  if (tid == 0) ringcnt = 0;
  if (tid < 64) {
    ebest[tid] = ~0ull;
    rm1_u[tid] = 0x7F7FFFFFu;  // +FLT_MAX
  }

  // ---- A tile: linear 32KB copy image->LDS (wave-uniform base + lane*16).
  // Bound = 8: 8 iters x 4 waves x 1KB = 32KB exactly (R6's bug was 16). ----
  const u16* Atile = Xh + (size_t)blockIdx.x * 32768;
  u16* AsF = &As[0][0][0];
#pragma unroll
  for (int r = 0; r < 8; ++r)
    GLOAD_LDS16(Atile + r * 2048 + wid * 512 + lane * 8, AsF + r * 2048 + wid * 512);

  // ---- B pipeline start (kstep slice gs: 8KB at Eh + gs*4096) ----
  auto stage = [&](int bufi, int gs) {
    const u16* g = Eh + (size_t)gs * 4096 + wid * 1024 + lane * 8;
    u16* l = &Bs[bufi][wid * 1024];
    GLOAD_LDS16(g, l);
    GLOAD_LDS16(g + 512, l + 512);
  };
  stage(0, 0);
  stage(1, 1);

  const float4* x4 = reinterpret_cast<const float4*>(x);
  if (tid < 64) {
    const float4* xr = x4 + (size_t)(rowbase + tid) * 64;
    float2 p0 = pairwise128_sq_abs_v4(xr);
    float2 p1 = pairwise128_sq_abs_v4(xr + 32);
    xsq_s[tid] = p0.x + p1.x;
    // Rigorous per-row band threshold (>=2x margin over the derived
    // |approx-exact| dist bound 1.94e-6*Sa + 1.24e-4). Harness-proven in
    // three prior passing rounds -- do not tighten.
    th_s[tid] = 4.0e-6f * (p0.y + p1.y) + 4.0e-4f;
  }

  // per-thread constant LDS offsets (u16 units)
  int offA[2], offB[4];
#pragma unroll
  for (int mf = 0; mf < 2; ++mf) {
    const int row = wm * 32 + mf * 16 + (lane & 15);
    offA[mf] = row * 32 + (((lane >> 4) ^ swz4(row)) * 8);
  }
#pragma unroll
  for (int nf = 0; nf < 4; ++nf) {
    const int cl = wn * 64 + nf * 16 + (lane & 15);
    offB[nf] = cl * 32 + (((lane >> 4) ^ swz4(cl)) * 8);
  }

  f32x4 acc[2][4];
#pragma unroll
  for (int mf = 0; mf < 2; ++mf)
#pragma unroll
    for (int nf = 0; nf < 4; ++nf) acc[mf][nf] = (f32x4){0.f, 0.f, 0.f, 0.f};

  asm volatile("s_waitcnt vmcnt(0)");
  __syncthreads();

  int bufc = 0;
#pragma unroll 1
  for (int chunk = 0; chunk < 16; ++chunk) {
    // esq loads issued at chunk start; oldest in the VMEM queue, so the
    // per-kstep vmcnt(4) drains them without draining the stage pipeline.
    float esq_c[4];
#pragma unroll
    for (int nf = 0; nf < 4; ++nf)
      esq_c[nf] = esq_g[chunk * 128 + wn * 64 + nf * 16 + (lane & 15)];
#pragma unroll
    for (int ks = 0; ks < 8; ++ks) {
      const int gs = chunk * 8 + ks;
      const bool dostage = (gs + 2 < 128);
      if (dostage) {
        int b2 = bufc + 2;
        if (b2 >= 3) b2 -= 3;
        stage(b2, gs + 2);
      }
      const u16* aa = &As[ks][0][0];
      const u16* bb = &Bs[bufc][0];
      f16x8 afr[2], bfr[4];
#pragma unroll
      for (int mf = 0; mf < 2; ++mf)
        afr[mf] = *reinterpret_cast<const f16x8*>(aa + offA[mf]);
#pragma unroll
      for (int nf = 0; nf < 4; ++nf)
        bfr[nf] = *reinterpret_cast<const f16x8*>(bb + offB[nf]);
#pragma unroll
      for (int mf = 0; mf < 2; ++mf)
#pragma unroll
        for (int nf = 0; nf < 4; ++nf)
          acc[mf][nf] = __builtin_amdgcn_mfma_f32_16x16x32_f16(
              afr[mf], bfr[nf], acc[mf][nf], 0, 0, 0);
      if (dostage) asm volatile("s_waitcnt vmcnt(4)");
      else asm volatile("s_waitcnt vmcnt(0)");
      __builtin_amdgcn_s_barrier();
      if (++bufc == 3) bufc = 0;
    }
    // ---- pass 1: per-row chunk min -> rm1 (shuffle-reduced, 1 atomic/row).
    // Warms the gate BEFORE any recording: chunk 0 cannot flood the ring. ----
#pragma unroll
    for (int mf = 0; mf < 2; ++mf) {
#pragma unroll
      for (int rg = 0; rg < 4; ++rg) {
        const int row = wm * 32 + mf * 16 + (lane >> 4) * 4 + rg;  // C layout (m89)
        const float xq = xsq_s[row];
        float dmin = 3.4e38f;
#pragma unroll
        for (int nf = 0; nf < 4; ++nf)
          dmin = fminf(dmin, (xq - 2.0f * acc[mf][nf][rg]) + esq_c[nf]);
        dmin = fminf(dmin, __shfl_xor(dmin, 1, 64));
        dmin = fminf(dmin, __shfl_xor(dmin, 2, 64));
        dmin = fminf(dmin, __shfl_xor(dmin, 4, 64));
        dmin = fminf(dmin, __shfl_xor(dmin, 8, 64));
        if ((lane & 15) == 0) atomicMin(&rm1_u[row], __float_as_uint(dmin));
      }
    }
    __syncthreads();
    // ---- pass 2: record with post-chunk-min gate (sound: rm >= final min
    // always, th >= 2*err -> true winner and all possible ties recorded) ----
    const int cbase = chunk * 128 + wn * 64;
#pragma unroll
    for (int mf = 0; mf < 2; ++mf) {
#pragma unroll
      for (int rg = 0; rg < 4; ++rg) {
        const int row = wm * 32 + mf * 16 + (lane >> 4) * 4 + rg;
        const float xq = xsq_s[row];
        const float gate = __uint_as_float(rm1_u[row]) + th_s[row];
#pragma unroll
        for (int nf = 0; nf < 4; ++nf) {
          const float dv = (xq - 2.0f * acc[mf][nf][rg]) + esq_c[nf];
          if (dv <= gate) {
            unsigned slot = atomicAdd(&ringcnt, 1u);
            if (slot < RINGCAP)
              ring[slot] = ((unsigned)row << 11) |
                           (unsigned)(cbase + nf * 16 + (lane & 15));
          }
          acc[mf][nf][rg] = 0.0f;
        }
      }
    }
  }
  __syncthreads();

  // ---- exact rescoring of every ring entry (winner + all ties provably in) --
  const float4* e4 = reinterpret_cast<const float4*>(e);
  const unsigned cnt = ringcnt;
  if (cnt <= RINGCAP) {
    for (unsigned i = tid; i < cnt; i += 256) {
      const unsigned ent = ring[i];
      const int row = (int)(ent >> 11), code = (int)(ent & 2047u);
      const float cr = exact_cross(x4, e4, rowbase + row, code);
      const float d = (xsq_s[row] - 2.0f * cr) + esq_g[code];
      const unsigned long long key =
          (((unsigned long long)__float_as_uint(d)) << 32) | (unsigned)code;
      atomicMin(&ebest[row], key);  // min dist, tie -> lowest code (np rule)
    }
  } else {  // overflow (statistically unreachable): full exact scan
#pragma unroll 1
    for (int row = 0; row < 64; ++row) {
      for (int code = tid; code < K_SZ; code += 256) {
        const float cr = exact_cross(x4, e4, rowbase + row, code);
        const float d = (xsq_s[row] - 2.0f * cr) + esq_g[code];
        const unsigned long long key =
            (((unsigned long long)__float_as_uint(d)) << 32) | (unsigned)code;
        atomicMin(&ebest[row], key);
      }
    }
  }
  __syncthreads();
  if (tid < 64) fidx[tid] = (int)(ebest[tid] & 2047ull);
  __syncthreads();

  // ---- output: gather + STE, fully coalesced; overwrites this block's own
  // (already fully consumed) Xh tile region ----
  float4* out4 = reinterpret_cast<float4*>(out);
#pragma unroll 1
  for (int i = tid; i < 64 * 64; i += 256) {
    const int row = i >> 6, q = i & 63;
    const int idx = fidx[row];
    float4 xv = x4[(size_t)(rowbase + row) * 64 + q];
    float4 qv = e4[(size_t)idx * 64 + q];
    float4 o;
    o.x = xv.x + (qv.x - xv.x);
    o.y = xv.y + (qv.y - xv.y);
    o.z = xv.z + (qv.z - xv.z);
    o.w = xv.w + (qv.w - xv.w);
    out4[(size_t)(rowbase + row) * 64 + q] = o;
    if (q == 0) outIdx[rowbase + row] = (float)idx;
  }
}

extern "C" void kernel_launch(void* const* d_in, const int* in_sizes, int n_in,
                              void* d_out, int out_size, void* d_ws, size_t ws_size,
                              hipStream_t stream) {
  const float* x = (const float*)d_in[0];  // (65536, 256) fp32
  const float* e = (const float*)d_in[1];  // (2048, 256) fp32
  float* out = (float*)d_out;              // [T*D quantized | T indices-as-float]
  float* outIdx = out + (size_t)T_SZ * D_SZ;

  float* esq = (float*)d_ws;     // 2048 floats
  u16* Eh = (u16*)(esq + K_SZ);  // 1 MB fp16 codebook image
  // Xh (fp16 x image, 64KB-stride tiles) lives in the quantized-output region:
  // block b reads only tile b (prologue) and overwrites that region at the end.
  u16* Xh = (u16*)out;

  conv_x_kernel<<<T_SZ / 64, 256, 0, stream>>>(x, Xh);
  conv_e_kernel<<<K_SZ / 128, 256, 0, stream>>>(e, Eh);
  esq_kernel<<<K_SZ / 64, 64, 0, stream>>>(e, esq);
  vq_mfma_kernel<<<T_SZ / 64, 256, 0, stream>>>(x, e, Xh, Eh, esq, out, outIdx);
}

// Round 9
// 344.976 us; speedup vs baseline: 42.5483x; 1.2731x over previous
//
#include <hip/hip_runtime.h>

#define T_SZ 65536
#define K_SZ 2048
#define D_SZ 256

typedef unsigned short u16;
typedef _Float16 f16;
typedef f16 f16x8 __attribute__((ext_vector_type(8)));
typedef float f32x4 __attribute__((ext_vector_type(4)));

// Candidate ring capacity (per 64-row block). With the post-chunk-min gate
// (two-pass epilogue, R8-proven at speed) the load is ~winners + near-ties;
// 1024 is >4x headroom. Overflow -> exact full scan fallback (correct, slow,
// statistically unreachable with the warmed gate -- R7 proved both halves).
#define RINGCAP 1024

#define GLOAD_LDS16(g, l)                                                  \
  __builtin_amdgcn_global_load_lds(                                        \
      (const __attribute__((address_space(1))) unsigned int*)(g),          \
      (__attribute__((address_space(3))) unsigned int*)(l), 16, 0, 0)

// bank-swizzle key for 16B k-groups within a 64B row. Baked into the global
// fp16 images by the conv kernels and inverted at fragment-read time (G21:
// both-sides-or-neither), so it is correctness-neutral by construction.
__device__ __forceinline__ int swz4(int r) { return (r & 3) ^ ((r >> 2) & 3); }

// numpy pairwise_sum replica for 128 contiguous squared elements, float4
// loads (identical FP op sequence to the harness-verified scalar version).
__device__ __forceinline__ float pairwise128_sq_v4(const float4* __restrict__ a4) {
#pragma clang fp contract(off)
  float4 va = a4[0], vb = a4[1];
  float r0 = va.x * va.x, r1 = va.y * va.y, r2 = va.z * va.z, r3 = va.w * va.w;
  float r4 = vb.x * vb.x, r5 = vb.y * vb.y, r6 = vb.z * vb.z, r7 = vb.w * vb.w;
#pragma unroll
  for (int i = 2; i < 32; i += 2) {
    float4 c = a4[i], d = a4[i + 1];
    r0 += c.x * c.x;
    r1 += c.y * c.y;
    r2 += c.z * c.z;
    r3 += c.w * c.w;
    r4 += d.x * d.x;
    r5 += d.y * d.y;
    r6 += d.z * d.z;
    r7 += d.w * d.w;
  }
  return ((r0 + r1) + (r2 + r3)) + ((r4 + r5) + (r6 + r7));
}

// Same exact chain + loose |x| sum (only feeds our own rigorous error bound).
__device__ __forceinline__ float2 pairwise128_sq_abs_v4(const float4* __restrict__ a4) {
#pragma clang fp contract(off)
  float4 va = a4[0], vb = a4[1];
  float r0 = va.x * va.x, r1 = va.y * va.y, r2 = va.z * va.z, r3 = va.w * va.w;
  float r4 = vb.x * vb.x, r5 = vb.y * vb.y, r6 = vb.z * vb.z, r7 = vb.w * vb.w;
  float s0 = fabsf(va.x) + fabsf(va.y), s1 = fabsf(va.z) + fabsf(va.w);
  float s2 = fabsf(vb.x) + fabsf(vb.y), s3 = fabsf(vb.z) + fabsf(vb.w);
#pragma unroll
  for (int i = 2; i < 32; i += 2) {
    float4 c = a4[i], d = a4[i + 1];
    r0 += c.x * c.x;
    r1 += c.y * c.y;
    r2 += c.z * c.z;
    r3 += c.w * c.w;
    r4 += d.x * d.x;
    r5 += d.y * d.y;
    r6 += d.z * d.z;
    r7 += d.w * d.w;
    s0 += fabsf(c.x) + fabsf(c.y);
    s1 += fabsf(c.z) + fabsf(c.w);
    s2 += fabsf(d.x) + fabsf(d.y);
    s3 += fabsf(d.z) + fabsf(d.w);
  }
  float2 res;
  res.x = ((r0 + r1) + (r2 + r3)) + ((r4 + r5) + (r6 + r7));
  res.y = (s0 + s1) + (s2 + s3);
  return res;
}

__global__ void esq_kernel(const float* __restrict__ e, float* __restrict__ esq) {
  int k = blockIdx.x * 64 + threadIdx.x;
  const float4* er = reinterpret_cast<const float4*>(e + (size_t)k * D_SZ);
  esq[k] = pairwise128_sq_v4(er) + pairwise128_sq_v4(er + 32);
}

// E: fp32 rows -> pre-tiled, pre-swizzled fp16 image (RNE via v_cvt_f16_f32).
// Per 128-row tile (32768 u16): [kstep 0..7][row 0..127][G 0..3][j 0..7],
// element (row, k = kstep*32 + 8*(G ^ swz4(row)) + j).
__global__ __launch_bounds__(256) void conv_e_kernel(const float* __restrict__ src,
                                                     u16* __restrict__ dst) {
  const int tile = blockIdx.x, tid = threadIdx.x;
  const float4* s4 = reinterpret_cast<const float4*>(src);
  u16* dt = dst + (size_t)tile * 32768;
#pragma unroll 1
  for (int it = 0; it < 16; ++it) {
    int idx = tid + it * 256;  // 0..4095
    int G = idx & 3, row = (idx >> 2) & 127, step = idx >> 9;  // step 0..7
    int srow = tile * 128 + row;
    int kb = step * 32 + 8 * (G ^ swz4(row));
    float4 a = s4[srow * 64 + (kb >> 2)];
    float4 b = s4[srow * 64 + (kb >> 2) + 1];
    float v[8] = {a.x, a.y, a.z, a.w, b.x, b.y, b.z, b.w};
    union { f16 h[8]; uint4 vec; } pk;
#pragma unroll
    for (int j = 0; j < 8; ++j) pk.h[j] = (f16)v[j];
    *reinterpret_cast<uint4*>(dt + (size_t)step * 4096 + row * 32 + G * 8) = pk.vec;
  }
}

// X: same format, 64-row tiles (16384 u16 payload padded to 32768-u16 stride so
// tile b sits inside block b's OWN 64KB output region: no cross-block hazard).
__global__ __launch_bounds__(256) void conv_x_kernel(const float* __restrict__ src,
                                                     u16* __restrict__ dst) {
  const int tile = blockIdx.x, tid = threadIdx.x;
  const float4* s4 = reinterpret_cast<const float4*>(src);
  u16* dt = dst + (size_t)tile * 32768;
#pragma unroll 1
  for (int it = 0; it < 8; ++it) {
    int idx = tid + it * 256;  // 0..2047
    int G = idx & 3, row = (idx >> 2) & 63, step = idx >> 8;  // step 0..7
    int srow = tile * 64 + row;
    int kb = step * 32 + 8 * (G ^ swz4(row));
    float4 a = s4[srow * 64 + (kb >> 2)];
    float4 b = s4[srow * 64 + (kb >> 2) + 1];
    float v[8] = {a.x, a.y, a.z, a.w, b.x, b.y, b.z, b.w};
    union { f16 h[8]; uint4 vec; } pk;
#pragma unroll
    for (int j = 0; j < 8; ++j) pk.h[j] = (f16)v[j];
    *reinterpret_cast<uint4*>(dt + (size_t)step * 2048 + row * 32 + G * 8) = pk.vec;
  }
}

// Exact cross term: sequential fmaf chain over d=0..255 -- bit-identical to the
// harness-verified chain from previous rounds.
__device__ __forceinline__ float exact_cross(const float4* __restrict__ x4,
                                             const float4* __restrict__ e4,
                                             int grow, int code) {
  const float4* xr = x4 + (size_t)grow * 64;
  const float4* er = e4 + (size_t)code * 64;
  float acc = 0.0f;
#pragma unroll 8
  for (int t = 0; t < 64; ++t) {
    float4 a = xr[t], b = er[t];
    acc = __builtin_fmaf(a.x, b.x, acc);
    acc = __builtin_fmaf(a.y, b.y, acc);
    acc = __builtin_fmaf(a.z, b.z, acc);
    acc = __builtin_fmaf(a.w, b.w, acc);
  }
  return acc;
}

// Fused: fp16 MFMA GEMM. R9 structural test: B is read DIRECTLY from the
// L2-resident global image (each fragment read covers a contiguous 1KB line
// set -> fully coalesced); A stays in LDS (written once in the prologue).
// The K-loop has ZERO barriers / vmcnt asm / global_load_lds -- waves run
// independently and the compiler pipelines freely. This removes the
// per-kstep sync fabric that every 300+us round (R2/R5/R8) shared.
// Block = 256 thr (2x2 waves; wave tile 32 rows x 64 cols), grid 1024,
// LDS 38.4KB -> 4 blocks/CU (16 waves).
__global__ __launch_bounds__(256, 4) void vq_mfma_kernel(
    const float* __restrict__ x, const float* __restrict__ e,
    const u16* __restrict__ Xh, const u16* __restrict__ Eh,
    const float* __restrict__ esq_g, float* __restrict__ out,
    float* __restrict__ outIdx) {
  __shared__ __align__(16) u16 As[8][64][32];  // 32KB: [ks][row][Gj]
  __shared__ float xsq_s[64], th_s[64];
  __shared__ unsigned rm1_u[64];               // running min dist (uint-ordered)
  __shared__ unsigned ring[RINGCAP];
  __shared__ unsigned long long ebest[64];
  __shared__ int fidx[64];
  __shared__ unsigned ringcnt;

  const int tid = threadIdx.x;
  const int lane = tid & 63;
  const int wid = tid >> 6;
  const int wm = wid >> 1, wn = wid & 1;  // 2x2 wave grid
  const int rowbase = blockIdx.x * 64;

  if (tid == 0) ringcnt = 0;
  if (tid < 64) {
    ebest[tid] = ~0ull;
    rm1_u[tid] = 0x7F7FFFFFu;  // +FLT_MAX
  }

  // ---- A tile: linear 32KB copy image->LDS, once (8 x 4 waves x 1KB) ----
  const u16* Atile = Xh + (size_t)blockIdx.x * 32768;
  u16* AsF = &As[0][0][0];
#pragma unroll
  for (int r = 0; r < 8; ++r)
    GLOAD_LDS16(Atile + r * 2048 + wid * 512 + lane * 8, AsF + r * 2048 + wid * 512);

  const float4* x4 = reinterpret_cast<const float4*>(x);
  if (tid < 64) {
    const float4* xr = x4 + (size_t)(rowbase + tid) * 64;
    float2 p0 = pairwise128_sq_abs_v4(xr);
    float2 p1 = pairwise128_sq_abs_v4(xr + 32);
    xsq_s[tid] = p0.x + p1.x;
    // Rigorous per-row band threshold (>=2x margin over the derived
    // |approx-exact| dist bound 1.94e-6*Sa + 1.24e-4). Harness-proven in
    // four prior passing rounds -- do not tighten.
    th_s[tid] = 4.0e-6f * (p0.y + p1.y) + 4.0e-4f;
  }

  // per-thread constant offsets (u16 units)
  int offA[2], offB[4];
#pragma unroll
  for (int mf = 0; mf < 2; ++mf) {
    const int row = wm * 32 + mf * 16 + (lane & 15);
    offA[mf] = row * 32 + (((lane >> 4) ^ swz4(row)) * 8);
  }
#pragma unroll
  for (int nf = 0; nf < 4; ++nf) {
    const int cl = wn * 64 + nf * 16 + (lane & 15);
    offB[nf] = cl * 32 + (((lane >> 4) ^ swz4(cl)) * 8);  // within a kstep slice
  }

  f32x4 acc[2][4];
#pragma unroll
  for (int mf = 0; mf < 2; ++mf)
#pragma unroll
    for (int nf = 0; nf < 4; ++nf) acc[mf][nf] = (f32x4){0.f, 0.f, 0.f, 0.f};

  asm volatile("s_waitcnt vmcnt(0)");  // A-tile LDS writes complete
  __syncthreads();

#pragma unroll 1
  for (int chunk = 0; chunk < 16; ++chunk) {
    float esq_c[4];
#pragma unroll
    for (int nf = 0; nf < 4; ++nf)
      esq_c[nf] = esq_g[chunk * 128 + wn * 64 + nf * 16 + (lane & 15)];
    // B slice for this chunk: 8 ksteps x 8KB, streamed straight from L2.
    const u16* Bch = Eh + (size_t)chunk * 32768;
#pragma unroll
    for (int ks = 0; ks < 8; ++ks) {
      const u16* bg = Bch + ks * 4096;
      const u16* aa = &As[ks][0][0];
      f16x8 afr[2], bfr[4];
#pragma unroll
      for (int nf = 0; nf < 4; ++nf)
        bfr[nf] = *reinterpret_cast<const f16x8*>(bg + offB[nf]);
#pragma unroll
      for (int mf = 0; mf < 2; ++mf)
        afr[mf] = *reinterpret_cast<const f16x8*>(aa + offA[mf]);
#pragma unroll
      for (int mf = 0; mf < 2; ++mf)
#pragma unroll
        for (int nf = 0; nf < 4; ++nf)
          acc[mf][nf] = __builtin_amdgcn_mfma_f32_16x16x32_f16(
              afr[mf], bfr[nf], acc[mf][nf], 0, 0, 0);
    }
    // ---- pass 1: per-row chunk min -> rm1 (shuffle-reduced, 1 atomic/row).
    // Warms the gate BEFORE any recording: chunk 0 cannot flood the ring. ----
#pragma unroll
    for (int mf = 0; mf < 2; ++mf) {
#pragma unroll
      for (int rg = 0; rg < 4; ++rg) {
        const int row = wm * 32 + mf * 16 + (lane >> 4) * 4 + rg;  // C layout (m89)
        const float xq = xsq_s[row];
        float dmin = 3.4e38f;
#pragma unroll
        for (int nf = 0; nf < 4; ++nf)
          dmin = fminf(dmin, (xq - 2.0f * acc[mf][nf][rg]) + esq_c[nf]);
        dmin = fminf(dmin, __shfl_xor(dmin, 1, 64));
        dmin = fminf(dmin, __shfl_xor(dmin, 2, 64));
        dmin = fminf(dmin, __shfl_xor(dmin, 4, 64));
        dmin = fminf(dmin, __shfl_xor(dmin, 8, 64));
        if ((lane & 15) == 0) atomicMin(&rm1_u[row], __float_as_uint(dmin));
      }
    }
    __syncthreads();
    // ---- pass 2: record with post-chunk-min gate (sound: rm >= final min
    // always, th >= 2*err -> true winner and all possible ties recorded) ----
    const int cbase = chunk * 128 + wn * 64;
#pragma unroll
    for (int mf = 0; mf < 2; ++mf) {
#pragma unroll
      for (int rg = 0; rg < 4; ++rg) {
        const int row = wm * 32 + mf * 16 + (lane >> 4) * 4 + rg;
        const float xq = xsq_s[row];
        const float gate = __uint_as_float(rm1_u[row]) + th_s[row];
#pragma unroll
        for (int nf = 0; nf < 4; ++nf) {
          const float dv = (xq - 2.0f * acc[mf][nf][rg]) + esq_c[nf];
          if (dv <= gate) {
            unsigned slot = atomicAdd(&ringcnt, 1u);
            if (slot < RINGCAP)
              ring[slot] = ((unsigned)row << 11) |
                           (unsigned)(cbase + nf * 16 + (lane & 15));
          }
          acc[mf][nf][rg] = 0.0f;
        }
      }
    }
    __syncthreads();  // rm1 stable before next chunk's pass-1 atomics
  }

  // ---- exact rescoring of every ring entry (winner + all ties provably in) --
  const float4* e4 = reinterpret_cast<const float4*>(e);
  const unsigned cnt = ringcnt;
  if (cnt <= RINGCAP) {
    for (unsigned i = tid; i < cnt; i += 256) {
      const unsigned ent = ring[i];
      const int row = (int)(ent >> 11), code = (int)(ent & 2047u);
      const float cr = exact_cross(x4, e4, rowbase + row, code);
      const float d = (xsq_s[row] - 2.0f * cr) + esq_g[code];
      const unsigned long long key =
          (((unsigned long long)__float_as_uint(d)) << 32) | (unsigned)code;
      atomicMin(&ebest[row], key);  // min dist, tie -> lowest code (np rule)
    }
  } else {  // overflow (statistically unreachable): full exact scan
#pragma unroll 1
    for (int row = 0; row < 64; ++row) {
      for (int code = tid; code < K_SZ; code += 256) {
        const float cr = exact_cross(x4, e4, rowbase + row, code);
        const float d = (xsq_s[row] - 2.0f * cr) + esq_g[code];
        const unsigned long long key =
            (((unsigned long long)__float_as_uint(d)) << 32) | (unsigned)code;
        atomicMin(&ebest[row], key);
      }
    }
  }
  __syncthreads();
  if (tid < 64) fidx[tid] = (int)(ebest[tid] & 2047ull);
  __syncthreads();

  // ---- output: gather + STE, fully coalesced; overwrites this block's own
  // (already fully consumed) Xh tile region ----
  float4* out4 = reinterpret_cast<float4*>(out);
#pragma unroll 1
  for (int i = tid; i < 64 * 64; i += 256) {
    const int row = i >> 6, q = i & 63;
    const int idx = fidx[row];
    float4 xv = x4[(size_t)(rowbase + row) * 64 + q];
    float4 qv = e4[(size_t)idx * 64 + q];
    float4 o;
    o.x = xv.x + (qv.x - xv.x);
    o.y = xv.y + (qv.y - xv.y);
    o.z = xv.z + (qv.z - xv.z);
    o.w = xv.w + (qv.w - xv.w);
    out4[(size_t)(rowbase + row) * 64 + q] = o;
    if (q == 0) outIdx[rowbase + row] = (float)idx;
  }
}

extern "C" void kernel_launch(void* const* d_in, const int* in_sizes, int n_in,
                              void* d_out, int out_size, void* d_ws, size_t ws_size,
                              hipStream_t stream) {
  const float* x = (const float*)d_in[0];  // (65536, 256) fp32
  const float* e = (const float*)d_in[1];  // (2048, 256) fp32
  float* out = (float*)d_out;              // [T*D quantized | T indices-as-float]
  float* outIdx = out + (size_t)T_SZ * D_SZ;

  float* esq = (float*)d_ws;     // 2048 floats
  u16* Eh = (u16*)(esq + K_SZ);  // 1 MB fp16 codebook image
  // Xh (fp16 x image, 64KB-stride tiles) lives in the quantized-output region:
  // block b reads only tile b (prologue) and overwrites that region at the end.
  u16* Xh = (u16*)out;

  conv_x_kernel<<<T_SZ / 64, 256, 0, stream>>>(x, Xh);
  conv_e_kernel<<<K_SZ / 128, 256, 0, stream>>>(e, Eh);
  esq_kernel<<<K_SZ / 64, 64, 0, stream>>>(e, esq);
  vq_mfma_kernel<<<T_SZ / 64, 256, 0, stream>>>(x, e, Xh, Eh, esq, out, outIdx);
}

// Round 10
// 324.275 us; speedup vs baseline: 45.2645x; 1.0638x over previous
//
#include <hip/hip_runtime.h>

#define T_SZ 65536
#define K_SZ 2048
#define D_SZ 256

typedef unsigned short u16;
typedef _Float16 f16;
typedef f16 f16x8 __attribute__((ext_vector_type(8)));
typedef float f32x4 __attribute__((ext_vector_type(4)));

// Candidate ring capacity (per 64-row block). Post-chunk-min gate load is
// ~winners + near-ties; 1024 is >4x headroom. Overflow -> exact full scan
// fallback (correct, slow, statistically unreachable with the warmed gate).
#define RINGCAP 1024

// bank-swizzle key for 16B k-groups within a 64B row. Baked into the fp16
// operand layouts (E image by conv_e, A staging in-kernel) and inverted at
// fragment-read time (G21: both-sides-or-neither) -- correctness-neutral.
__device__ __forceinline__ int swz4(int r) { return (r & 3) ^ ((r >> 2) & 3); }

// numpy pairwise_sum replica for 128 contiguous squared elements, float4
// loads (identical FP op sequence to the harness-verified scalar version).
__device__ __forceinline__ float pairwise128_sq_v4(const float4* __restrict__ a4) {
#pragma clang fp contract(off)
  float4 va = a4[0], vb = a4[1];
  float r0 = va.x * va.x, r1 = va.y * va.y, r2 = va.z * va.z, r3 = va.w * va.w;
  float r4 = vb.x * vb.x, r5 = vb.y * vb.y, r6 = vb.z * vb.z, r7 = vb.w * vb.w;
#pragma unroll
  for (int i = 2; i < 32; i += 2) {
    float4 c = a4[i], d = a4[i + 1];
    r0 += c.x * c.x;
    r1 += c.y * c.y;
    r2 += c.z * c.z;
    r3 += c.w * c.w;
    r4 += d.x * d.x;
    r5 += d.y * d.y;
    r6 += d.z * d.z;
    r7 += d.w * d.w;
  }
  return ((r0 + r1) + (r2 + r3)) + ((r4 + r5) + (r6 + r7));
}

// Same exact chain + loose |x| sum (only feeds our own rigorous error bound).
__device__ __forceinline__ float2 pairwise128_sq_abs_v4(const float4* __restrict__ a4) {
#pragma clang fp contract(off)
  float4 va = a4[0], vb = a4[1];
  float r0 = va.x * va.x, r1 = va.y * va.y, r2 = va.z * va.z, r3 = va.w * va.w;
  float r4 = vb.x * vb.x, r5 = vb.y * vb.y, r6 = vb.z * vb.z, r7 = vb.w * vb.w;
  float s0 = fabsf(va.x) + fabsf(va.y), s1 = fabsf(va.z) + fabsf(va.w);
  float s2 = fabsf(vb.x) + fabsf(vb.y), s3 = fabsf(vb.z) + fabsf(vb.w);
#pragma unroll
  for (int i = 2; i < 32; i += 2) {
    float4 c = a4[i], d = a4[i + 1];
    r0 += c.x * c.x;
    r1 += c.y * c.y;
    r2 += c.z * c.z;
    r3 += c.w * c.w;
    r4 += d.x * d.x;
    r5 += d.y * d.y;
    r6 += d.z * d.z;
    r7 += d.w * d.w;
    s0 += fabsf(c.x) + fabsf(c.y);
    s1 += fabsf(c.z) + fabsf(c.w);
    s2 += fabsf(d.x) + fabsf(d.y);
    s3 += fabsf(d.z) + fabsf(d.w);
  }
  float2 res;
  res.x = ((r0 + r1) + (r2 + r3)) + ((r4 + r5) + (r6 + r7));
  res.y = (s0 + s1) + (s2 + s3);
  return res;
}

__global__ void esq_kernel(const float* __restrict__ e, float* __restrict__ esq) {
  int k = blockIdx.x * 64 + threadIdx.x;
  const float4* er = reinterpret_cast<const float4*>(e + (size_t)k * D_SZ);
  esq[k] = pairwise128_sq_v4(er) + pairwise128_sq_v4(er + 32);
}

// E: fp32 rows -> pre-tiled, pre-swizzled fp16 image (RNE via v_cvt_f16_f32).
// Per 128-row tile (32768 u16): [kstep 0..7][row 0..127][G 0..3][j 0..7],
// element (row, k = kstep*32 + 8*(G ^ swz4(row)) + j).
__global__ __launch_bounds__(256) void conv_e_kernel(const float* __restrict__ src,
                                                     u16* __restrict__ dst) {
  const int tile = blockIdx.x, tid = threadIdx.x;
  const float4* s4 = reinterpret_cast<const float4*>(src);
  u16* dt = dst + (size_t)tile * 32768;
#pragma unroll 1
  for (int it = 0; it < 16; ++it) {
    int idx = tid + it * 256;  // 0..4095
    int G = idx & 3, row = (idx >> 2) & 127, step = idx >> 9;  // step 0..7
    int srow = tile * 128 + row;
    int kb = step * 32 + 8 * (G ^ swz4(row));
    float4 a = s4[srow * 64 + (kb >> 2)];
    float4 b = s4[srow * 64 + (kb >> 2) + 1];
    float v[8] = {a.x, a.y, a.z, a.w, b.x, b.y, b.z, b.w};
    union { f16 h[8]; uint4 vec; } pk;
#pragma unroll
    for (int j = 0; j < 8; ++j) pk.h[j] = (f16)v[j];
    *reinterpret_cast<uint4*>(dt + (size_t)step * 4096 + row * 32 + G * 8) = pk.vec;
  }
}

// Exact cross term: sequential fmaf chain over d=0..255 -- bit-identical to the
// harness-verified chain from previous rounds.
__device__ __forceinline__ float exact_cross(const float4* __restrict__ x4,
                                             const float4* __restrict__ e4,
                                             int grow, int code) {
  const float4* xr = x4 + (size_t)grow * 64;
  const float4* er = e4 + (size_t)code * 64;
  float acc = 0.0f;
#pragma unroll 8
  for (int t = 0; t < 64; ++t) {
    float4 a = xr[t], b = er[t];
    acc = __builtin_fmaf(a.x, b.x, acc);
    acc = __builtin_fmaf(a.y, b.y, acc);
    acc = __builtin_fmaf(a.z, b.z, acc);
    acc = __builtin_fmaf(a.w, b.w, acc);
  }
  return acc;
}

// Fused: fp16 MFMA GEMM, barrier-free K-loop (R9-proven), B read directly
// from the L2-resident global image with SOURCE-LEVEL DOUBLE-BUFFERED
// PREFETCH (R9's VGPR=64 showed zero prefetch depth -> every kstep ate a raw
// ~200cy L2 latency; alternating static buffers give each load a full
// MFMA-phase of cover, x4 waves/SIMD). A is converted fp32->fp16 IN-KERNEL
// into LDS via ds_write (same layout/cvt as the old conv_x image + copy,
// byte-identical), killing the conv_x kernel and ~96MB of HBM traffic.
// Two-pass post-chunk-min gated ring, exact rescoring, gather + STE output.
// Block = 256 thr (2x2 waves; wave tile 32 rows x 64 cols), grid 1024,
// LDS 38.7KB -> 4 blocks/CU.
__global__ __launch_bounds__(256, 4) void vq_mfma_kernel(
    const float* __restrict__ x, const float* __restrict__ e,
    const u16* __restrict__ Eh, const float* __restrict__ esq_g,
    float* __restrict__ out, float* __restrict__ outIdx) {
  __shared__ __align__(16) u16 As[8][64][32];  // 32KB: [ks][row][Gj]
  __shared__ float xsq_s[64], th_s[64];
  __shared__ unsigned rm1_u[64];               // running min dist (uint-ordered)
  __shared__ unsigned ring[RINGCAP];
  __shared__ unsigned long long ebest[64];
  __shared__ int fidx[64];
  __shared__ unsigned ringcnt;

  const int tid = threadIdx.x;
  const int lane = tid & 63;
  const int wm = (tid >> 6) >> 1, wn = (tid >> 6) & 1;  // 2x2 wave grid
  const int rowbase = blockIdx.x * 64;

  if (tid == 0) ringcnt = 0;
  if (tid < 64) {
    ebest[tid] = ~0ull;
    rm1_u[tid] = 0x7F7FFFFFu;  // +FLT_MAX
  }

  const float4* x4 = reinterpret_cast<const float4*>(x);

  // ---- A staging: convert this block's 64 x-rows to fp16 directly into LDS.
  // Same element mapping as the old conv_x image (k = ks*32+8*(G^swz4(row))+j
  // at As[ks][row][G*8]); contiguous 1KB ds_write coverage per step. ----
  const float4* xt4 = x4 + (size_t)rowbase * 64;
#pragma unroll 2
  for (int it = 0; it < 8; ++it) {
    int idx = tid + it * 256;  // 0..2047
    int G = idx & 3, row = (idx >> 2) & 63, ks = idx >> 8;
    int kb = ks * 32 + 8 * (G ^ swz4(row));
    float4 a = xt4[(size_t)row * 64 + (kb >> 2)];
    float4 b = xt4[(size_t)row * 64 + (kb >> 2) + 1];
    union { f16 h[8]; uint4 vec; } pk;
    pk.h[0] = (f16)a.x; pk.h[1] = (f16)a.y; pk.h[2] = (f16)a.z; pk.h[3] = (f16)a.w;
    pk.h[4] = (f16)b.x; pk.h[5] = (f16)b.y; pk.h[6] = (f16)b.z; pk.h[7] = (f16)b.w;
    *reinterpret_cast<uint4*>(&As[ks][row][G * 8]) = pk.vec;
  }

  if (tid < 64) {
    const float4* xr = x4 + (size_t)(rowbase + tid) * 64;  // L1/L2-hot now
    float2 p0 = pairwise128_sq_abs_v4(xr);
    float2 p1 = pairwise128_sq_abs_v4(xr + 32);
    xsq_s[tid] = p0.x + p1.x;
    // Rigorous per-row band threshold (>=2x margin over the derived
    // |approx-exact| dist bound 1.94e-6*Sa + 1.24e-4). Harness-proven in
    // five prior passing rounds -- do not tighten.
    th_s[tid] = 4.0e-6f * (p0.y + p1.y) + 4.0e-4f;
  }

  // per-thread constant offsets (u16 units)
  int offA[2], offB[4];
#pragma unroll
  for (int mf = 0; mf < 2; ++mf) {
    const int row = wm * 32 + mf * 16 + (lane & 15);
    offA[mf] = row * 32 + (((lane >> 4) ^ swz4(row)) * 8);
  }
#pragma unroll
  for (int nf = 0; nf < 4; ++nf) {
    const int cl = wn * 64 + nf * 16 + (lane & 15);
    offB[nf] = cl * 32 + (((lane >> 4) ^ swz4(cl)) * 8);  // within a kstep slice
  }

  f32x4 acc[2][4];
#pragma unroll
  for (int mf = 0; mf < 2; ++mf)
#pragma unroll
    for (int nf = 0; nf < 4; ++nf) acc[mf][nf] = (f32x4){0.f, 0.f, 0.f, 0.f};

  // B prefetch: preload gs=0 into parity buffer 0 (global, no barrier dep).
  f16x8 bpf[2][4];
#pragma unroll
  for (int nf = 0; nf < 4; ++nf)
    bpf[0][nf] = *reinterpret_cast<const f16x8*>(Eh + offB[nf]);

  __syncthreads();  // A staging (ds_write) + xsq/th visible to all waves

#pragma unroll 1
  for (int chunk = 0; chunk < 16; ++chunk) {
    float esq_c[4];
#pragma unroll
    for (int nf = 0; nf < 4; ++nf)
      esq_c[nf] = esq_g[chunk * 128 + wn * 64 + nf * 16 + (lane & 15)];
#pragma unroll
    for (int ks = 0; ks < 8; ++ks) {       // fully unrolled: par is static
      const int par = ks & 1;
      const int gsn = chunk * 8 + ks + 1;  // next kstep (crosses chunks)
      if (gsn < 128) {
        const u16* bg = Eh + (size_t)gsn * 4096;
#pragma unroll
        for (int nf = 0; nf < 4; ++nf)
          bpf[par ^ 1][nf] = *reinterpret_cast<const f16x8*>(bg + offB[nf]);
      }
      const u16* aa = &As[ks][0][0];
      f16x8 afr[2];
#pragma unroll
      for (int mf = 0; mf < 2; ++mf)
        afr[mf] = *reinterpret_cast<const f16x8*>(aa + offA[mf]);
#pragma unroll
      for (int mf = 0; mf < 2; ++mf)
#pragma unroll
        for (int nf = 0; nf < 4; ++nf)
          acc[mf][nf] = __builtin_amdgcn_mfma_f32_16x16x32_f16(
              afr[mf], bpf[par][nf], acc[mf][nf], 0, 0, 0);
    }
    // ---- pass 1: per-row chunk min -> rm1 (shuffle-reduced, 1 atomic/row).
    // Warms the gate BEFORE any recording: chunk 0 cannot flood the ring. ----
#pragma unroll
    for (int mf = 0; mf < 2; ++mf) {
#pragma unroll
      for (int rg = 0; rg < 4; ++rg) {
        const int row = wm * 32 + mf * 16 + (lane >> 4) * 4 + rg;  // C layout (m89)
        const float xq = xsq_s[row];
        float dmin = 3.4e38f;
#pragma unroll
        for (int nf = 0; nf < 4; ++nf)
          dmin = fminf(dmin, (xq - 2.0f * acc[mf][nf][rg]) + esq_c[nf]);
        dmin = fminf(dmin, __shfl_xor(dmin, 1, 64));
        dmin = fminf(dmin, __shfl_xor(dmin, 2, 64));
        dmin = fminf(dmin, __shfl_xor(dmin, 4, 64));
        dmin = fminf(dmin, __shfl_xor(dmin, 8, 64));
        if ((lane & 15) == 0) atomicMin(&rm1_u[row], __float_as_uint(dmin));
      }
    }
    __syncthreads();
    // ---- pass 2: record with post-chunk-min gate. Sound: rm_used >= rm_final
    // always (monotone atomicMin), th >= 2*err -> winner + all possible ties
    // recorded. No trailing barrier needed: next chunk's pass-1 atomics only
    // LOWER rm1, and any rm_used >= rm_final keeps the guarantee. ----
    const int cbase = chunk * 128 + wn * 64;
#pragma unroll
    for (int mf = 0; mf < 2; ++mf) {
#pragma unroll
      for (int rg = 0; rg < 4; ++rg) {
        const int row = wm * 32 + mf * 16 + (lane >> 4) * 4 + rg;
        const float xq = xsq_s[row];
        const float gate = __uint_as_float(rm1_u[row]) + th_s[row];
#pragma unroll
        for (int nf = 0; nf < 4; ++nf) {
          const float dv = (xq - 2.0f * acc[mf][nf][rg]) + esq_c[nf];
          if (dv <= gate) {
            unsigned slot = atomicAdd(&ringcnt, 1u);
            if (slot < RINGCAP)
              ring[slot] = ((unsigned)row << 11) |
                           (unsigned)(cbase + nf * 16 + (lane & 15));
          }
          acc[mf][nf][rg] = 0.0f;
        }
      }
    }
  }
  __syncthreads();

  // ---- exact rescoring of every ring entry (winner + all ties provably in) --
  const float4* e4 = reinterpret_cast<const float4*>(e);
  const unsigned cnt = ringcnt;
  if (cnt <= RINGCAP) {
    for (unsigned i = tid; i < cnt; i += 256) {
      const unsigned ent = ring[i];
      const int row = (int)(ent >> 11), code = (int)(ent & 2047u);
      const float cr = exact_cross(x4, e4, rowbase + row, code);
      const float d = (xsq_s[row] - 2.0f * cr) + esq_g[code];
      const unsigned long long key =
          (((unsigned long long)__float_as_uint(d)) << 32) | (unsigned)code;
      atomicMin(&ebest[row], key);  // min dist, tie -> lowest code (np rule)
    }
  } else {  // overflow (statistically unreachable): full exact scan
#pragma unroll 1
    for (int row = 0; row < 64; ++row) {
      for (int code = tid; code < K_SZ; code += 256) {
        const float cr = exact_cross(x4, e4, rowbase + row, code);
        const float d = (xsq_s[row] - 2.0f * cr) + esq_g[code];
        const unsigned long long key =
            (((unsigned long long)__float_as_uint(d)) << 32) | (unsigned)code;
        atomicMin(&ebest[row], key);
      }
    }
  }
  __syncthreads();
  if (tid < 64) fidx[tid] = (int)(ebest[tid] & 2047ull);
  __syncthreads();

  // ---- output: gather + STE, fully coalesced ----
  float4* out4 = reinterpret_cast<float4*>(out);
#pragma unroll 1
  for (int i = tid; i < 64 * 64; i += 256) {
    const int row = i >> 6, q = i & 63;
    const int idx = fidx[row];
    float4 xv = x4[(size_t)(rowbase + row) * 64 + q];
    float4 qv = e4[(size_t)idx * 64 + q];
    float4 o;
    o.x = xv.x + (qv.x - xv.x);
    o.y = xv.y + (qv.y - xv.y);
    o.z = xv.z + (qv.z - xv.z);
    o.w = xv.w + (qv.w - xv.w);
    out4[(size_t)(rowbase + row) * 64 + q] = o;
    if (q == 0) outIdx[rowbase + row] = (float)idx;
  }
}

extern "C" void kernel_launch(void* const* d_in, const int* in_sizes, int n_in,
                              void* d_out, int out_size, void* d_ws, size_t ws_size,
                              hipStream_t stream) {
  const float* x = (const float*)d_in[0];  // (65536, 256) fp32
  const float* e = (const float*)d_in[1];  // (2048, 256) fp32
  float* out = (float*)d_out;              // [T*D quantized | T indices-as-float]
  float* outIdx = out + (size_t)T_SZ * D_SZ;

  float* esq = (float*)d_ws;     // 2048 floats
  u16* Eh = (u16*)(esq + K_SZ);  // 1 MB fp16 codebook image

  conv_e_kernel<<<K_SZ / 128, 256, 0, stream>>>(e, Eh);
  esq_kernel<<<K_SZ / 64, 64, 0, stream>>>(e, esq);
  vq_mfma_kernel<<<T_SZ / 64, 256, 0, stream>>>(x, e, Eh, esq, out, outIdx);
}